// Round 7
// baseline (168.376 us; speedup 1.0000x reference)
//
#include <hip/hip_runtime.h>
#include <cstdint>
#include <cstddef>

typedef int   v4i __attribute__((ext_vector_type(4)));
typedef float v4f __attribute__((ext_vector_type(4)));
typedef unsigned int u32;

constexpr int B_   = 64;
constexpr int CIN  = 96;
constexpr int P_   = 784;     // 28*28
constexpr int CMID = 576;
constexpr int COUT = 96;
constexpr int NOUT = B_ * COUT * P_;
constexpr float NBITF = 127.0f;
constexpr float EPSF  = 1e-5f;
constexpr float MAGICF = 12582912.0f;    // 1.5 * 2^23
constexpr int   BIASI  = 0x4B400000;     // float bits of MAGICF (low byte 0)

// x8t2: v4i X[b][pt 13][g 8][pxl 64] = k-bytes 16g..16g+15 of px pt*64+pxl
//   (g 0..5 = ic 0..95, g 6..7 = zero K-pad 96->128). One MFMA A-frag = 1 v4i.
constexpr int XB4 = 13 * 8 * 64;        // v4i per batch (6656)
constexpr int Y1S = 42;                 // y1 ch-stride = exactly 42 window
                                        // words; even stride verified <=2-way
                                        // on all dw/tr4/conv1 patterns.

__device__ __forceinline__ int dot3(u32 a, u32 w, int acc) {
#if __has_builtin(__builtin_amdgcn_sdot4)
    return __builtin_amdgcn_sdot4((int)a, (int)w, acc, false);
#else
    return acc + (int)(signed char)(a)        * (int)(signed char)(w)
               + (int)(signed char)(a >> 8)   * (int)(signed char)(w >> 8)
               + (int)(signed char)(a >> 16)  * (int)(signed char)(w >> 16);
#endif
}

__device__ __forceinline__ void tr4(u32 S0, u32 S1, u32 S2, u32 S3, u32 O[4]) {
    u32 u01 = __builtin_amdgcn_perm(S1, S0, 0x05010400u);
    u32 u23 = __builtin_amdgcn_perm(S3, S2, 0x05010400u);
    u32 v01 = __builtin_amdgcn_perm(S1, S0, 0x07030602u);
    u32 v23 = __builtin_amdgcn_perm(S3, S2, 0x07030602u);
    O[0] = __builtin_amdgcn_perm(u23, u01, 0x05040100u);
    O[1] = __builtin_amdgcn_perm(u23, u01, 0x07060302u);
    O[2] = __builtin_amdgcn_perm(v23, v01, 0x05040100u);
    O[3] = __builtin_amdgcn_perm(v23, v01, 0x07060302u);
}

__device__ __forceinline__ u32 pack4(u32 t0, u32 t1, u32 t2, u32 t3) {
    u32 p01 = __builtin_amdgcn_perm(t1, t0, 0x05010400u);
    u32 p23 = __builtin_amdgcn_perm(t3, t2, 0x05010400u);
    return __builtin_amdgcn_perm(p23, p01, 0x05040100u);
}

// ---------------------------------------------------------------------------
// prep_all: blocks [0,448) = quant_x into x8t2; blocks [448,760) = weight
// prep (4 single-wave jobs/block) emitting int8 levels + folded epilogue
// constants e1/e2/e3 = {scale, bias} per channel. (R7: restored from R4 —
// the one-time x8t2 build amortizes the quant work the R5/R6 fused variant
// repeated per block.)
// ---------------------------------------------------------------------------
__global__ __launch_bounds__(256)
void prep_all(const float* __restrict__ x,
              const float* __restrict__ w1, const float* __restrict__ g1,
              const float* __restrict__ b1, const float* __restrict__ m1,
              const float* __restrict__ v1,
              const float* __restrict__ w2, const float* __restrict__ g2,
              const float* __restrict__ b2, const float* __restrict__ m2,
              const float* __restrict__ v2,
              const float* __restrict__ w3, const float* __restrict__ g3,
              const float* __restrict__ b3, const float* __restrict__ m3,
              const float* __restrict__ v3,
              const float* __restrict__ r0, const float* __restrict__ r1,
              const float* __restrict__ r2, const int* __restrict__ cluster,
              u32* __restrict__ x8t2,
              int8_t* __restrict__ w1qp, float2* __restrict__ e1,
              v4i* __restrict__ w2pk,    float2* __restrict__ e2,
              int8_t* __restrict__ w3qp, float2* __restrict__ e3)
{
    __shared__ u32 T[112 * 37];
    int tid = threadIdx.x;
    int c = cluster[0];

    if (blockIdx.x < 448) {
        int pt0 = blockIdx.x % 7, b = blockIdx.x / 7;
        float inv_s0 = NBITF / r0[c];

        for (int i = tid; i < 112 * 8; i += 256) {      // zero kdw 24..31
            int row = i >> 3, cc = 24 + (i & 7);
            T[row * 37 + cc] = 0u;
        }
        for (int u = tid; u < 24 * 28; u += 256) {
            int pq = u % 28, icq = u / 28;
            int pxb = pt0 * 112 + pq * 4;
            int q[4][4];
            #pragma unroll
            for (int j = 0; j < 4; j++) {
                v4f xv = *(const v4f*)(x + ((size_t)b * CIN + icq * 4 + j) * P_ + pxb);
                #pragma unroll
                for (int i = 0; i < 4; i++)
                    q[j][i] = (int)fminf(fmaxf(rintf(xv[i] * inv_s0), -127.f), 127.f);
            }
            #pragma unroll
            for (int i = 0; i < 4; i++) {
                u32 t0 = __builtin_amdgcn_perm((u32)q[1][i], (u32)q[0][i], 0x00000400u);
                u32 t1 = __builtin_amdgcn_perm((u32)q[3][i], (u32)q[2][i], 0x00000400u);
                T[(pq * 4 + i) * 37 + icq] = __builtin_amdgcn_perm(t1, t0, 0x05040100u);
            }
        }
        __syncthreads();
        u32* gb = x8t2 + (size_t)b * XB4 * 4;
        for (int i = tid; i < 32 * 112; i += 256) {
            int icq = i / 112, pxo = i - icq * 112;
            int px = pt0 * 112 + pxo;
            gb[(((px >> 6) * 8 + (icq >> 2)) * 64 + (px & 63)) * 4 + (icq & 3)] =
                T[pxo * 37 + icq];
        }
        return;
    }

    int lane = tid & 63, wv = tid >> 6;
    int blk = (blockIdx.x - 448) * 4 + wv;   // 0..1247

    const float *w, *g, *bb, *mm, *vv;
    int oc, K, which;
    if (blk < CMID)            { which = 0; w = w1; g = g1; bb = b1; mm = m1; vv = v1; oc = blk;            K = CIN;  }
    else if (blk < 2 * CMID)   { which = 1; w = w2; g = g2; bb = b2; mm = m2; vv = v2; oc = blk - CMID;     K = 9;    }
    else                       { which = 2; w = w3; g = g3; bb = b3; mm = m3; vv = v3; oc = blk - 2 * CMID; K = CMID; }

    float scale = g[oc] / sqrtf(vv[oc] + EPSF);

    float mx = 0.f;
    for (int k = lane; k < K; k += 64)
        mx = fmaxf(mx, fabsf(w[oc * K + k] * scale));
    #pragma unroll
    for (int off = 1; off < 64; off <<= 1)
        mx = fmaxf(mx, __shfl_xor(mx, off));

    float s = mx / NBITF;

    int myq = 0;
    for (int k = lane; k < K; k += 64) {
        float wf = w[oc * K + k] * scale;
        float q  = fminf(fmaxf(rintf(wf / s), -127.f), 127.f);
        if (which == 0)      w1qp[oc * 144 + k] = (int8_t)q;
        else if (which == 1) myq = (int)q;
        else                 w3qp[oc * 592 + k] = (int8_t)q;
    }
    if (which == 0 && lane < 12)
        ((u32*)(w1qp + oc * 144))[24 + lane] = 0u;
    if (which == 1) {
        u32 qq[9];
        #pragma unroll
        for (int t = 0; t < 9; t++) qq[t] = (u32)__shfl(myq, t, 64) & 0xffu;
        if (lane == 0) {
            v4i pk;
            pk[0] = (int)(qq[0] | (qq[1] << 8) | (qq[2] << 16));
            pk[1] = (int)(qq[3] | (qq[4] << 8) | (qq[5] << 16));
            pk[2] = (int)(qq[6] | (qq[7] << 8) | (qq[8] << 16));
            pk[3] = 0;
            w2pk[oc] = pk;
        }
    }
    if (lane == 0) {
        float bf = bb[oc] - mm[oc] * scale;
        float s0 = r0[c] / NBITF, s1 = r1[c] / NBITF, s2 = r2[c] / NBITF;
        if (which == 0) {
            float inv_s1 = NBITF / r1[c];
            e1[oc] = make_float2(s0 * s * inv_s1, bf * inv_s1);
        } else if (which == 1) {
            float inv_s2 = NBITF / r2[c];
            e2[oc] = make_float2(s1 * s * inv_s2, bf * inv_s2);
        } else {
            e3[oc] = make_float2(s2 * s, bf);
        }
    }
}

// ---------------------------------------------------------------------------
// conv123d R7: RBLK=4 (R6's halo-overcompute win) at 3 blocks/CU (R4's
// occupancy). A-frags read from global x8t2 (R3 proved LDS xw staging is
// time-neutral; dropping it + the R6 per-block quant saves 22.5 KB LDS and
// ~1200 VALU/block). Y1S=42, bank-checked <=2-way. LDS 53760 B = 105
// granules -> 3 blocks/CU = 12 waves/CU (the session-measured knee).
// Grid (7 rt, 64 b).
// ---------------------------------------------------------------------------
__global__ __launch_bounds__(256, 3)
void conv123d(const v4i* __restrict__ x8t2, const v4i* __restrict__ w1q4,
              const float2* __restrict__ e1,
              const v4i* __restrict__ w2pk, const float2* __restrict__ e2,
              const int8_t* __restrict__ w3qp, const float2* __restrict__ e3,
              const float* __restrict__ x,
              const float* __restrict__ r1, const float* __restrict__ r2,
              const float* __restrict__ r3, const int* __restrict__ cluster,
              float* __restrict__ out)
{
    __shared__ u32 y1s[4][48 * Y1S];    // per-wave scratch  32256 B
    __shared__ v4i y2c[12 * 112];       // per-phase slice   21504 B

    int tid = threadIdx.x, b = blockIdx.y, rt = blockIdx.x;
    int R0 = 4 * rt;
    int W0 = (R0 - 1) * 28;             // window px base (may be -28)
    int lane = tid & 63, wv = tid >> 6;
    int n = lane & 15, q4 = lane >> 4;

    int   c      = cluster[0];
    int   u1i    = (int)fminf(rintf(6.f * NBITF / r1[c]), 127.f);
    int   u2i    = (int)fminf(rintf(6.f * NBITF / r2[c]), 127.f);
    float s3     = r3[c] / NBITF;
    float inv_s3 = NBITF / r3[c];

    // window A-frag base offsets (reused across phases; L1/L2-resident)
    const v4i* xb = x8t2 + (size_t)b * XB4;
    int pb[11];
    #pragma unroll
    for (int jm = 0; jm < 11; jm++) {
        int px = min(max(W0 + 16 * jm + n, 0), P_ - 1);
        pb[jm] = (px >> 6) * 512 + (px & 63);
    }

    u32* myY1 = y1s[wv];

    // conv3 state (persistent across phases): 2 px-groups x 6 oc-groups
    int pxl0 = wv * 32 + n;              // px group h=0
    int pxc0 = min(pxl0, 111);
    int pxc1 = min(pxl0 + 16, 111);
    const v4i* w34 = (const v4i*)w3qp;   // 37 v4i per oc row
    v4i acc3[2][6];
    #pragma unroll
    for (int h = 0; h < 2; h++)
        #pragma unroll
        for (int i = 0; i < 6; i++) acc3[h][i] = (v4i){0, 0, 0, 0};

    for (int ph = 0; ph < 3; ph++) {
        int oc0 = ph * 192 + wv * 48;    // contiguous 192-ch slice per phase

        // ---- conv1: 48 oc x 42 words, jm-outer with jn inner ----
        v4i    bw[3][2];
        float2 ee[3];
        #pragma unroll
        for (int jn = 0; jn < 3; jn++) {
            int oc = oc0 + 16 * jn + n;
            bw[jn][0] = w1q4[oc * 9 + q4];
            bw[jn][1] = w1q4[oc * 9 + 4 + q4];
            ee[jn] = e1[oc];
        }
        #pragma unroll
        for (int jm = 0; jm < 11; jm++) {
            v4i af0 = xb[pb[jm] + q4 * 64];
            v4i af1 = xb[pb[jm] + (4 + q4) * 64];
            int dw = 4 * jm + q4;                       // 0..43 (42,43 dead)
            bool inimg = (unsigned)(W0 + 4 * dw) < (unsigned)P_;

            #pragma unroll
            for (int jn = 0; jn < 3; jn++) {
                v4i acc = (v4i){0, 0, 0, 0};
                acc = __builtin_amdgcn_mfma_i32_16x16x64_i8(af0, bw[jn][0], acc, 0, 0, 0);
                acc = __builtin_amdgcn_mfma_i32_16x16x64_i8(af1, bw[jn][1], acc, 0, 0, 0);
                u32 t[4];
                #pragma unroll
                for (int r = 0; r < 4; r++) {
                    float f = fmaf((float)acc[r], ee[jn].x, ee[jn].y) + MAGICF;
                    t[r] = (u32)min(max(__float_as_int(f), BIASI), BIASI + u1i);
                }
                u32 pk = pack4(t[0], t[1], t[2], t[3]);
                if (dw < 42)
                    myY1[(16 * jn + n) * Y1S + dw] = inimg ? pk : 0u;
            }
        }

        // ---- depthwise 3x3: 48 ch x 4 orows = 192 units = 3 passes.
        //      Unit = one full output row: preload 21 window words into
        //      regs, fence, compute 7 words, store in-place over window
        //      row 'orow'. Each channel's 4 units sit in one pass; the
        //      sched_barrier keeps every lane's reads ahead of stores.
        #pragma unroll
        for (int p = 0; p < 3; p++) {
            int id   = p * 64 + lane;
            int chl  = id >> 2;                 // 0..47
            int orow = id & 3;                  // 0..3
            int ch   = oc0 + chl;
            int rb   = chl * Y1S + orow * 7;    // first window row base

            v4i wpk = w2pk[ch];
            u32 pk0 = (u32)wpk[0], pk1 = (u32)wpk[1], pk2 = (u32)wpk[2];
            float2 e = e2[ch];

            u32 W[3][7];
            #pragma unroll
            for (int r = 0; r < 3; r++)
                #pragma unroll
                for (int w = 0; w < 7; w++)
                    W[r][w] = myY1[rb + r * 7 + w];

            __builtin_amdgcn_sched_barrier(0);  // all reads before stores

            u32 outw[7];
            #pragma unroll
            for (int xq = 0; xq < 7; xq++) {
                u32 M0 = xq ? W[0][xq - 1] : 0u;
                u32 M1 = xq ? W[1][xq - 1] : 0u;
                u32 M2 = xq ? W[2][xq - 1] : 0u;
                u32 D0 = W[0][xq], D1 = W[1][xq], D2 = W[2][xq];
                u32 N0 = (xq < 6) ? W[0][xq + 1] : 0u;
                u32 N1 = (xq < 6) ? W[1][xq + 1] : 0u;
                u32 N2 = (xq < 6) ? W[2][xq + 1] : 0u;

                int a0, a1, a2, a3;
                a0 = dot3(__builtin_amdgcn_alignbyte(D0, M0, 3), pk0, 0);
                a0 = dot3(__builtin_amdgcn_alignbyte(D1, M1, 3), pk1, a0);
                a0 = dot3(__builtin_amdgcn_alignbyte(D2, M2, 3), pk2, a0);
                a1 = dot3(D0, pk0, 0);
                a1 = dot3(D1, pk1, a1);
                a1 = dot3(D2, pk2, a1);
                a2 = dot3(__builtin_amdgcn_alignbyte(N0, D0, 1), pk0, 0);
                a2 = dot3(__builtin_amdgcn_alignbyte(N1, D1, 1), pk1, a2);
                a2 = dot3(__builtin_amdgcn_alignbyte(N2, D2, 1), pk2, a2);
                a3 = dot3(__builtin_amdgcn_alignbyte(N0, D0, 2), pk0, 0);
                a3 = dot3(__builtin_amdgcn_alignbyte(N1, D1, 2), pk1, a3);
                a3 = dot3(__builtin_amdgcn_alignbyte(N2, D2, 2), pk2, a3);

                int aa[4] = {a0, a1, a2, a3};
                u32 tq[4];
                #pragma unroll
                for (int i = 0; i < 4; i++) {
                    float f = fmaf((float)aa[i], e.x, e.y) + MAGICF;
                    tq[i] = (u32)min(max(__float_as_int(f), BIASI), BIASI + u2i);
                }
                outw[xq] = pack4(tq[0], tq[1], tq[2], tq[3]);
            }

            #pragma unroll
            for (int xq = 0; xq < 7; xq++)
                myY1[chl * Y1S + orow * 7 + xq] = outw[xq];
        }

        // ---- tr4 -> shared ch-packed y2c slice (84 units) ----
        for (int u = lane; u < 84; u += 64) {
            int kgl = u / 28, d = u - kgl * 28;         // kgl 0..2, d 0..27
            u32 O[4][4];
            #pragma unroll
            for (int j = 0; j < 4; j++) {
                int ch0 = 16 * kgl + 4 * j;
                tr4(myY1[(ch0 + 0) * Y1S + d], myY1[(ch0 + 1) * Y1S + d],
                    myY1[(ch0 + 2) * Y1S + d], myY1[(ch0 + 3) * Y1S + d], O[j]);
            }
            int kgG = wv * 3 + kgl;                     // 0..11 within phase
            #pragma unroll
            for (int i = 0; i < 4; i++)
                y2c[kgG * 112 + 4 * d + i] =
                    (v4i){(int)O[0][i], (int)O[1][i], (int)O[2][i], (int)O[3][i]};
        }

        __syncthreads();   // y2c slice complete

        // ---- conv3 partial-K MFMA: 12 k-slices, A-frags reused over h ----
        #pragma unroll
        for (int ks = 0; ks < 3; ks++) {
            v4i bfr0 = y2c[(4 * ks + q4) * 112 + pxc0];
            v4i bfr1 = y2c[(4 * ks + q4) * 112 + pxc1];
            #pragma unroll
            for (int i = 0; i < 6; i++) {
                v4i afr = w34[(i * 16 + n) * 37 + ph * 12 + 4 * ks + q4];
                acc3[0][i] = __builtin_amdgcn_mfma_i32_16x16x64_i8(afr, bfr0, acc3[0][i], 0, 0, 0);
                acc3[1][i] = __builtin_amdgcn_mfma_i32_16x16x64_i8(afr, bfr1, acc3[1][i], 0, 0, 0);
            }
        }

        if (ph < 2) __syncthreads();   // before next phase overwrites y2c
    }

    // ---- residual + requant epilogue ----
    #pragma unroll
    for (int h = 0; h < 2; h++) {
        int pxl = pxl0 + 16 * h;
        if (pxl < 112) {
            int px = R0 * 28 + pxl;
            #pragma unroll
            for (int i = 0; i < 6; i++) {
                #pragma unroll
                for (int r = 0; r < 4; r++) {
                    int    oc = i * 16 + q4 * 4 + r;
                    float2 e  = e3[oc];
                    size_t gi = (size_t)(b * COUT + oc) * P_ + px;
                    float v  = fmaf((float)acc3[h][i][r], e.x, e.y) + x[gi];
                    float f  = fmaf(v, inv_s3, MAGICF);
                    int lvl  = min(max(__float_as_int(f) - BIASI, -127), 127);
                    out[gi]  = (float)lvl * s3;
                }
            }
        }
    }
    if (rt == 0 && b == 0 && tid == 0)
        out[NOUT] = s3;
}

// ---------------------------------------------------------------------------
extern "C" void kernel_launch(void* const* d_in, const int* in_sizes, int n_in,
                              void* d_out, int out_size, void* d_ws, size_t ws_size,
                              hipStream_t stream)
{
    const float* x  = (const float*)d_in[0];
    const float* w1 = (const float*)d_in[1];
    const float* g1 = (const float*)d_in[2];
    const float* b1 = (const float*)d_in[3];
    const float* m1 = (const float*)d_in[4];
    const float* v1 = (const float*)d_in[5];
    const float* w2 = (const float*)d_in[6];
    const float* g2 = (const float*)d_in[7];
    const float* b2 = (const float*)d_in[8];
    const float* m2 = (const float*)d_in[9];
    const float* v2 = (const float*)d_in[10];
    const float* w3 = (const float*)d_in[11];
    const float* g3 = (const float*)d_in[12];
    const float* b3 = (const float*)d_in[13];
    const float* m3 = (const float*)d_in[14];
    const float* v3 = (const float*)d_in[15];
    const float* r0 = (const float*)d_in[16];
    const float* r1 = (const float*)d_in[17];
    const float* r2 = (const float*)d_in[18];
    const float* r3 = (const float*)d_in[19];
    const int*   cl = (const int*)d_in[20];

    float* out = (float*)d_out;

    char*  ws  = (char*)d_ws;
    size_t off = 0;
    auto carve = [&](size_t bytes) {
        size_t cur = off;
        off = (off + bytes + 255) & ~(size_t)255;
        return (void*)(ws + cur);
    };
    int8_t* w1qp = (int8_t*)carve((size_t)CMID * 144);
    float2* e1   = (float2*)carve((size_t)CMID * 8);
    v4i*    w2pk = (v4i*)carve((size_t)CMID * 16);
    float2* e2   = (float2*)carve((size_t)CMID * 8);
    int8_t* w3qp = (int8_t*)carve((size_t)COUT * 592);
    float2* e3   = (float2*)carve((size_t)COUT * 8);
    u32*    x8t2 = (u32*)carve((size_t)B_ * XB4 * 16);   // 6.8 MB
    (void)ws_size; (void)in_sizes; (void)n_in; (void)out_size;

    prep_all<<<dim3(760), dim3(256), 0, stream>>>(
        x, w1, g1, b1, m1, v1, w2, g2, b2, m2, v2, w3, g3, b3, m3, v3,
        r0, r1, r2, cl, x8t2,
        w1qp, e1, w2pk, e2, w3qp, e3);

    conv123d<<<dim3(7, B_), dim3(256), 0, stream>>>(
        (const v4i*)x8t2, (const v4i*)w1qp, e1, w2pk, e2, w3qp, e3,
        x, r1, r2, r3, cl, out);
}

// Round 8
// 154.692 us; speedup vs baseline: 1.0885x; 1.0885x over previous
//
#include <hip/hip_runtime.h>
#include <cstdint>
#include <cstddef>

typedef int   v4i __attribute__((ext_vector_type(4)));
typedef float v4f __attribute__((ext_vector_type(4)));
typedef unsigned int u32;

constexpr int B_   = 64;
constexpr int CIN  = 96;
constexpr int P_   = 784;     // 28*28
constexpr int CMID = 576;
constexpr int COUT = 96;
constexpr int NOUT = B_ * COUT * P_;
constexpr float NBITF = 127.0f;
constexpr float EPSF  = 1e-5f;
constexpr float MAGICF = 12582912.0f;    // 1.5 * 2^23
constexpr int   BIASI  = 0x4B400000;     // float bits of MAGICF (low byte 0)

constexpr int Y1S = 43;                 // y1 ch-stride: 42 window words + 1
                                        // pad (odd -> <=2-way on dw/tr4)

__device__ __forceinline__ int dot3(u32 a, u32 w, int acc) {
#if __has_builtin(__builtin_amdgcn_sdot4)
    return __builtin_amdgcn_sdot4((int)a, (int)w, acc, false);
#else
    return acc + (int)(signed char)(a)        * (int)(signed char)(w)
               + (int)(signed char)(a >> 8)   * (int)(signed char)(w >> 8)
               + (int)(signed char)(a >> 16)  * (int)(signed char)(w >> 16);
#endif
}

__device__ __forceinline__ void tr4(u32 S0, u32 S1, u32 S2, u32 S3, u32 O[4]) {
    u32 u01 = __builtin_amdgcn_perm(S1, S0, 0x05010400u);
    u32 u23 = __builtin_amdgcn_perm(S3, S2, 0x05010400u);
    u32 v01 = __builtin_amdgcn_perm(S1, S0, 0x07030602u);
    u32 v23 = __builtin_amdgcn_perm(S3, S2, 0x07030602u);
    O[0] = __builtin_amdgcn_perm(u23, u01, 0x05040100u);
    O[1] = __builtin_amdgcn_perm(u23, u01, 0x07060302u);
    O[2] = __builtin_amdgcn_perm(v23, v01, 0x05040100u);
    O[3] = __builtin_amdgcn_perm(v23, v01, 0x07060302u);
}

__device__ __forceinline__ u32 pack4(u32 t0, u32 t1, u32 t2, u32 t3) {
    u32 p01 = __builtin_amdgcn_perm(t1, t0, 0x05010400u);
    u32 p23 = __builtin_amdgcn_perm(t3, t2, 0x05010400u);
    return __builtin_amdgcn_perm(p23, p01, 0x05040100u);
}

// ---------------------------------------------------------------------------
// prep_w: weights-only prep. 312 blocks x 4 single-wave jobs emitting int8
// levels + folded epilogue constants e1/e2/e3. (R6-verified.)
// ---------------------------------------------------------------------------
__global__ __launch_bounds__(256)
void prep_w(const float* __restrict__ w1, const float* __restrict__ g1,
            const float* __restrict__ b1, const float* __restrict__ m1,
            const float* __restrict__ v1,
            const float* __restrict__ w2, const float* __restrict__ g2,
            const float* __restrict__ b2, const float* __restrict__ m2,
            const float* __restrict__ v2,
            const float* __restrict__ w3, const float* __restrict__ g3,
            const float* __restrict__ b3, const float* __restrict__ m3,
            const float* __restrict__ v3,
            const float* __restrict__ r0, const float* __restrict__ r1,
            const float* __restrict__ r2, const int* __restrict__ cluster,
            int8_t* __restrict__ w1qp, float2* __restrict__ e1,
            v4i* __restrict__ w2pk,    float2* __restrict__ e2,
            int8_t* __restrict__ w3qp, float2* __restrict__ e3)
{
    int tid = threadIdx.x;
    int c = cluster[0];
    int lane = tid & 63, wv = tid >> 6;
    int blk = blockIdx.x * 4 + wv;   // 0..1247

    const float *w, *g, *bb, *mm, *vv;
    int oc, K, which;
    if (blk < CMID)            { which = 0; w = w1; g = g1; bb = b1; mm = m1; vv = v1; oc = blk;            K = CIN;  }
    else if (blk < 2 * CMID)   { which = 1; w = w2; g = g2; bb = b2; mm = m2; vv = v2; oc = blk - CMID;     K = 9;    }
    else                       { which = 2; w = w3; g = g3; bb = b3; mm = m3; vv = v3; oc = blk - 2 * CMID; K = CMID; }

    float scale = g[oc] / sqrtf(vv[oc] + EPSF);

    float mx = 0.f;
    for (int k = lane; k < K; k += 64)
        mx = fmaxf(mx, fabsf(w[oc * K + k] * scale));
    #pragma unroll
    for (int off = 1; off < 64; off <<= 1)
        mx = fmaxf(mx, __shfl_xor(mx, off));

    float s = mx / NBITF;

    int myq = 0;
    for (int k = lane; k < K; k += 64) {
        float wf = w[oc * K + k] * scale;
        float q  = fminf(fmaxf(rintf(wf / s), -127.f), 127.f);
        if (which == 0)      w1qp[oc * 144 + k] = (int8_t)q;
        else if (which == 1) myq = (int)q;
        else                 w3qp[oc * 592 + k] = (int8_t)q;
    }
    if (which == 0 && lane < 12)
        ((u32*)(w1qp + oc * 144))[24 + lane] = 0u;
    if (which == 1) {
        u32 qq[9];
        #pragma unroll
        for (int t = 0; t < 9; t++) qq[t] = (u32)__shfl(myq, t, 64) & 0xffu;
        if (lane == 0) {
            v4i pk;
            pk[0] = (int)(qq[0] | (qq[1] << 8) | (qq[2] << 16));
            pk[1] = (int)(qq[3] | (qq[4] << 8) | (qq[5] << 16));
            pk[2] = (int)(qq[6] | (qq[7] << 8) | (qq[8] << 16));
            pk[3] = 0;
            w2pk[oc] = pk;
        }
    }
    if (lane == 0) {
        float bf = bb[oc] - mm[oc] * scale;
        float s0 = r0[c] / NBITF, s1 = r1[c] / NBITF, s2 = r2[c] / NBITF;
        if (which == 0) {
            float inv_s1 = NBITF / r1[c];
            e1[oc] = make_float2(s0 * s * inv_s1, bf * inv_s1);
        } else if (which == 1) {
            float inv_s2 = NBITF / r2[c];
            e2[oc] = make_float2(s1 * s * inv_s2, bf * inv_s2);
        } else {
            e3[oc] = make_float2(s2 * s, bf);
        }
    }
}

// ---------------------------------------------------------------------------
// conv123d R8 = R6 (best bench total: fused quant, RBLK=4, 2 blk/CU) plus:
//  (a) y2c px-swizzle s(px)=28*(px&3)+(px>>2): the old 4d+i layout made the
//      epilogue ds_write_b128 a 14-way bank conflict (lanes d,d+2 share a
//      4-bank group); swizzled writes hit the 28-lane b128 floor (4-way),
//      reads land 2-way (free).
//  (b) xw drops the g=6,7 zero slabs (5.6 KB + zero-fill pass); af1 is fed
//      a zero register for q4>=2 (K-pad 96->128 lives in those lanes).
// LDS 71424 B, 2 blocks/CU. Grid (7 rt, 64 b).
// ---------------------------------------------------------------------------
__global__ __launch_bounds__(256, 2)
void conv123d(const v4i* __restrict__ w1q4,
              const float2* __restrict__ e1,
              const v4i* __restrict__ w2pk, const float2* __restrict__ e2,
              const int8_t* __restrict__ w3qp, const float2* __restrict__ e3,
              const float* __restrict__ x,
              const float* __restrict__ r0,
              const float* __restrict__ r1, const float* __restrict__ r2,
              const float* __restrict__ r3, const int* __restrict__ cluster,
              float* __restrict__ out)
{
    __shared__ v4i xw[11 * 6 * 16];     // quantized x window 16896 B
    __shared__ u32 y1s[4][48 * Y1S];    // per-wave scratch   33024 B
    __shared__ v4i y2c[12 * 112];       // per-phase slice    21504 B

    int tid = threadIdx.x, b = blockIdx.y, rt = blockIdx.x;
    int R0 = 4 * rt;
    int W0 = (R0 - 1) * 28;             // window px base (may be -28)
    int lane = tid & 63, wv = tid >> 6;
    int n = lane & 15, q4 = lane >> 4;

    int   c      = cluster[0];
    float inv_s0 = NBITF / r0[c];
    int   u1i    = (int)fminf(rintf(6.f * NBITF / r1[c]), 127.f);
    int   u2i    = (int)fminf(rintf(6.f * NBITF / r2[c]), 127.f);
    float s3     = r3[c] / NBITF;
    float inv_s3 = NBITF / r3[c];

    // ---- quantize x window into LDS (once per block) ----
    for (int i = tid; i < 4224; i += 256) {
        int nn = i & 15;
        int q  = (i >> 4) & 3;
        int gj = i >> 6;                 // 0..65
        int g  = gj % 6, jm = gj / 6;    // g 0..5, jm 0..10
        int px = min(max(W0 + 16 * jm + nn, 0), P_ - 1);
        const float* xp = x + ((size_t)b * CIN + 16 * g + 4 * q) * P_ + px;
        int qv[4];
        #pragma unroll
        for (int j = 0; j < 4; j++) {
            float xf = xp[j * P_];
            qv[j] = (int)fminf(fmaxf(rintf(xf * inv_s0), -127.f), 127.f);
        }
        u32 t0 = __builtin_amdgcn_perm((u32)qv[1], (u32)qv[0], 0x00000400u);
        u32 t1 = __builtin_amdgcn_perm((u32)qv[3], (u32)qv[2], 0x00000400u);
        ((u32*)xw)[((jm * 6 + g) * 16 + nn) * 4 + q] =
            __builtin_amdgcn_perm(t1, t0, 0x05040100u);
    }

    u32* myY1 = y1s[wv];

    // conv3 state (persistent across phases): 2 px-groups x 6 oc-groups
    int pxl0 = wv * 32 + n;              // px group h=0
    int pxc0 = min(pxl0, 111);
    int pxc1 = min(pxl0 + 16, 111);
    int sx0  = 28 * (pxc0 & 3) + (pxc0 >> 2);   // swizzled y2c slots
    int sx1  = 28 * (pxc1 & 3) + (pxc1 >> 2);
    const v4i* w34 = (const v4i*)w3qp;   // 37 v4i per oc row
    v4i acc3[2][6];
    #pragma unroll
    for (int h = 0; h < 2; h++)
        #pragma unroll
        for (int i = 0; i < 6; i++) acc3[h][i] = (v4i){0, 0, 0, 0};

    __syncthreads();   // xw ready

    for (int ph = 0; ph < 3; ph++) {
        int oc0 = ph * 192 + wv * 48;    // contiguous 192-ch slice per phase

        // ---- conv1: 48 oc x 42 words, jm-outer with jn inner ----
        v4i    bw[3][2];
        float2 ee[3];
        #pragma unroll
        for (int jn = 0; jn < 3; jn++) {
            int oc = oc0 + 16 * jn + n;
            bw[jn][0] = w1q4[oc * 9 + q4];
            bw[jn][1] = w1q4[oc * 9 + 4 + q4];
            ee[jn] = e1[oc];
        }
        #pragma unroll
        for (int jm = 0; jm < 11; jm++) {
            v4i af0 = xw[(jm * 6 + q4) * 16 + n];
            v4i af1 = (q4 < 2) ? xw[(jm * 6 + 4 + q4) * 16 + n]
                               : (v4i){0, 0, 0, 0};
            int dw = 4 * jm + q4;                       // 0..43 (42,43 dead)
            bool inimg = (unsigned)(W0 + 4 * dw) < (unsigned)P_;

            #pragma unroll
            for (int jn = 0; jn < 3; jn++) {
                v4i acc = (v4i){0, 0, 0, 0};
                acc = __builtin_amdgcn_mfma_i32_16x16x64_i8(af0, bw[jn][0], acc, 0, 0, 0);
                acc = __builtin_amdgcn_mfma_i32_16x16x64_i8(af1, bw[jn][1], acc, 0, 0, 0);
                u32 t[4];
                #pragma unroll
                for (int r = 0; r < 4; r++) {
                    float f = fmaf((float)acc[r], ee[jn].x, ee[jn].y) + MAGICF;
                    t[r] = (u32)min(max(__float_as_int(f), BIASI), BIASI + u1i);
                }
                u32 pk = pack4(t[0], t[1], t[2], t[3]);
                if (dw < 42)
                    myY1[(16 * jn + n) * Y1S + dw] = inimg ? pk : 0u;
            }
        }

        // ---- depthwise 3x3: 48 ch x 4 orows = 192 units = 3 passes.
        //      Unit = one full output row: preload 21 window words into
        //      regs, fence, compute 7 words, store in-place over window
        //      row 'orow'. sched_barrier keeps reads ahead of stores.
        #pragma unroll
        for (int p = 0; p < 3; p++) {
            int id   = p * 64 + lane;
            int chl  = id >> 2;                 // 0..47
            int orow = id & 3;                  // 0..3
            int ch   = oc0 + chl;
            int rb   = chl * Y1S + orow * 7;    // first window row base

            v4i wpk = w2pk[ch];
            u32 pk0 = (u32)wpk[0], pk1 = (u32)wpk[1], pk2 = (u32)wpk[2];
            float2 e = e2[ch];

            u32 W[3][7];
            #pragma unroll
            for (int r = 0; r < 3; r++)
                #pragma unroll
                for (int w = 0; w < 7; w++)
                    W[r][w] = myY1[rb + r * 7 + w];

            __builtin_amdgcn_sched_barrier(0);  // all reads before stores

            u32 outw[7];
            #pragma unroll
            for (int xq = 0; xq < 7; xq++) {
                u32 M0 = xq ? W[0][xq - 1] : 0u;
                u32 M1 = xq ? W[1][xq - 1] : 0u;
                u32 M2 = xq ? W[2][xq - 1] : 0u;
                u32 D0 = W[0][xq], D1 = W[1][xq], D2 = W[2][xq];
                u32 N0 = (xq < 6) ? W[0][xq + 1] : 0u;
                u32 N1 = (xq < 6) ? W[1][xq + 1] : 0u;
                u32 N2 = (xq < 6) ? W[2][xq + 1] : 0u;

                int a0, a1, a2, a3;
                a0 = dot3(__builtin_amdgcn_alignbyte(D0, M0, 3), pk0, 0);
                a0 = dot3(__builtin_amdgcn_alignbyte(D1, M1, 3), pk1, a0);
                a0 = dot3(__builtin_amdgcn_alignbyte(D2, M2, 3), pk2, a0);
                a1 = dot3(D0, pk0, 0);
                a1 = dot3(D1, pk1, a1);
                a1 = dot3(D2, pk2, a1);
                a2 = dot3(__builtin_amdgcn_alignbyte(N0, D0, 1), pk0, 0);
                a2 = dot3(__builtin_amdgcn_alignbyte(N1, D1, 1), pk1, a2);
                a2 = dot3(__builtin_amdgcn_alignbyte(N2, D2, 1), pk2, a2);
                a3 = dot3(__builtin_amdgcn_alignbyte(N0, D0, 2), pk0, 0);
                a3 = dot3(__builtin_amdgcn_alignbyte(N1, D1, 2), pk1, a3);
                a3 = dot3(__builtin_amdgcn_alignbyte(N2, D2, 2), pk2, a3);

                int aa[4] = {a0, a1, a2, a3};
                u32 tq[4];
                #pragma unroll
                for (int i = 0; i < 4; i++) {
                    float f = fmaf((float)aa[i], e.x, e.y) + MAGICF;
                    tq[i] = (u32)min(max(__float_as_int(f), BIASI), BIASI + u2i);
                }
                outw[xq] = pack4(tq[0], tq[1], tq[2], tq[3]);
            }

            #pragma unroll
            for (int xq = 0; xq < 7; xq++)
                myY1[chl * Y1S + orow * 7 + xq] = outw[xq];
        }

        // ---- tr4 -> shared ch-packed y2c slice (84 units), px-swizzled:
        //      px 4d+i stored at slot 28i+d (4-way floor instead of 14-way).
        for (int u = lane; u < 84; u += 64) {
            int kgl = u / 28, d = u - kgl * 28;         // kgl 0..2, d 0..27
            u32 O[4][4];
            #pragma unroll
            for (int j = 0; j < 4; j++) {
                int ch0 = 16 * kgl + 4 * j;
                tr4(myY1[(ch0 + 0) * Y1S + d], myY1[(ch0 + 1) * Y1S + d],
                    myY1[(ch0 + 2) * Y1S + d], myY1[(ch0 + 3) * Y1S + d], O[j]);
            }
            int kgG = wv * 3 + kgl;                     // 0..11 within phase
            #pragma unroll
            for (int i = 0; i < 4; i++)
                y2c[kgG * 112 + 28 * i + d] =
                    (v4i){(int)O[0][i], (int)O[1][i], (int)O[2][i], (int)O[3][i]};
        }

        __syncthreads();   // y2c slice complete

        // ---- conv3 partial-K MFMA: 12 k-slices, A-frags reused over h ----
        #pragma unroll
        for (int ks = 0; ks < 3; ks++) {
            v4i bfr0 = y2c[(4 * ks + q4) * 112 + sx0];
            v4i bfr1 = y2c[(4 * ks + q4) * 112 + sx1];
            #pragma unroll
            for (int i = 0; i < 6; i++) {
                v4i afr = w34[(i * 16 + n) * 37 + ph * 12 + 4 * ks + q4];
                acc3[0][i] = __builtin_amdgcn_mfma_i32_16x16x64_i8(afr, bfr0, acc3[0][i], 0, 0, 0);
                acc3[1][i] = __builtin_amdgcn_mfma_i32_16x16x64_i8(afr, bfr1, acc3[1][i], 0, 0, 0);
            }
        }

        if (ph < 2) __syncthreads();   // before next phase overwrites y2c
    }

    // ---- residual + requant epilogue ----
    #pragma unroll
    for (int h = 0; h < 2; h++) {
        int pxl = pxl0 + 16 * h;
        if (pxl < 112) {
            int px = R0 * 28 + pxl;
            #pragma unroll
            for (int i = 0; i < 6; i++) {
                #pragma unroll
                for (int r = 0; r < 4; r++) {
                    int    oc = i * 16 + q4 * 4 + r;
                    float2 e  = e3[oc];
                    size_t gi = (size_t)(b * COUT + oc) * P_ + px;
                    float v  = fmaf((float)acc3[h][i][r], e.x, e.y) + x[gi];
                    float f  = fmaf(v, inv_s3, MAGICF);
                    int lvl  = min(max(__float_as_int(f) - BIASI, -127), 127);
                    out[gi]  = (float)lvl * s3;
                }
            }
        }
    }
    if (rt == 0 && b == 0 && tid == 0)
        out[NOUT] = s3;
}

// ---------------------------------------------------------------------------
extern "C" void kernel_launch(void* const* d_in, const int* in_sizes, int n_in,
                              void* d_out, int out_size, void* d_ws, size_t ws_size,
                              hipStream_t stream)
{
    const float* x  = (const float*)d_in[0];
    const float* w1 = (const float*)d_in[1];
    const float* g1 = (const float*)d_in[2];
    const float* b1 = (const float*)d_in[3];
    const float* m1 = (const float*)d_in[4];
    const float* v1 = (const float*)d_in[5];
    const float* w2 = (const float*)d_in[6];
    const float* g2 = (const float*)d_in[7];
    const float* b2 = (const float*)d_in[8];
    const float* m2 = (const float*)d_in[9];
    const float* v2 = (const float*)d_in[10];
    const float* w3 = (const float*)d_in[11];
    const float* g3 = (const float*)d_in[12];
    const float* b3 = (const float*)d_in[13];
    const float* m3 = (const float*)d_in[14];
    const float* v3 = (const float*)d_in[15];
    const float* r0 = (const float*)d_in[16];
    const float* r1 = (const float*)d_in[17];
    const float* r2 = (const float*)d_in[18];
    const float* r3 = (const float*)d_in[19];
    const int*   cl = (const int*)d_in[20];

    float* out = (float*)d_out;

    char*  ws  = (char*)d_ws;
    size_t off = 0;
    auto carve = [&](size_t bytes) {
        size_t cur = off;
        off = (off + bytes + 255) & ~(size_t)255;
        return (void*)(ws + cur);
    };
    int8_t* w1qp = (int8_t*)carve((size_t)CMID * 144);
    float2* e1   = (float2*)carve((size_t)CMID * 8);
    v4i*    w2pk = (v4i*)carve((size_t)CMID * 16);
    float2* e2   = (float2*)carve((size_t)CMID * 8);
    int8_t* w3qp = (int8_t*)carve((size_t)COUT * 592);
    float2* e3   = (float2*)carve((size_t)COUT * 8);
    (void)ws_size; (void)in_sizes; (void)n_in; (void)out_size;

    prep_w<<<dim3(312), dim3(256), 0, stream>>>(
        w1, g1, b1, m1, v1, w2, g2, b2, m2, v2, w3, g3, b3, m3, v3,
        r0, r1, r2, cl,
        w1qp, e1, w2pk, e2, w3qp, e3);

    conv123d<<<dim3(7, B_), dim3(256), 0, stream>>>(
        (const v4i*)w1qp, e1, w2pk, e2, w3qp, e3,
        x, r0, r1, r2, r3, cl, out);
}